// Round 18
// baseline (472.212 us; speedup 1.0000x reference)
//
#include <hip/hip_runtime.h>

typedef unsigned int u32;
typedef unsigned short u16;
typedef __attribute__((ext_vector_type(8))) short bf16x8;
typedef __attribute__((ext_vector_type(4))) float f32x4;
typedef __attribute__((ext_vector_type(4))) u32 u32x4;

// ---- problem constants ----
// B=256, C=1024, S=14, SS=196, C2=15, NCH=512, CAT=1551 (pad->1600), M=50176
// Triangular spatial: T=105 unique (i<=j) pairs; M' = 256*105 = 26,880
#define EPSBN 1e-5f

// async global->LDS, 16B per lane; LDS dest = wave-uniform base + lane*16 (linear in s)
#define GLDS16(gp, lp) __builtin_amdgcn_global_load_lds( \
    (const __attribute__((address_space(1))) u32*)(gp), \
    (__attribute__((address_space(3))) u32*)(lp), 16, 0, 0)

// ---- ws offsets (bytes) ----
#define OFF_ADW    0ull           // 50176*1600*2 = 160,563,200  (Adw bf16, K-padded)
#define OFF_COVT   0ull           // 26880*1024*2 = 55,050,240 (aliases Adw; dead before Adw written)
#define OFF_S      160563200ull   // 256*15*4
#define OFF_WBZ    160578560ull   // 512*1024*2 bf16 conv_w
#define OFF_WBP    161627136ull   // 512*1600*2 bf16 pw1_w padded
#define OFF_STATSZ 163265536ull   // 1024 f32 (sum,sumsq)
#define OFF_STATSO 163269632ull
#define OFF_SCZ    163273728ull
#define OFF_SHZ    163275776ull
#define OFF_SCO    163277824ull
#define OFF_SHO    163279872ull

static __device__ __forceinline__ float bf2f(u16 h){
  u32 u = ((u32)h) << 16; float f; __builtin_memcpy(&f, &u, 4); return f;
}
static __device__ __forceinline__ u16 f2bf(float f){
  u32 u; __builtin_memcpy(&u, &f, 4);
  u = (u + 0x7fffu + ((u >> 16) & 1u)) >> 16;
  return (u16)u;
}
// packed 2xf32 -> 2xbf16 (RNE) in ONE VALU op; no builtin on gfx950 -> inline asm (T12)
static __device__ __forceinline__ u32 pk2bf(float lo, float hi){
  u32 r;
  asm("v_cvt_pk_bf16_f32 %0, %1, %2" : "=v"(r) : "v"(lo), "v"(hi));
  return r;
}

// ---------------- SE block: s[b][15] = sigmoid(relu(g@fc1^T)@fc2^T) ----------------
__global__ __launch_bounds__(64) void se_kernel(const float* __restrict__ y,
    const float* __restrict__ fc1, const float* __restrict__ fc2, float* __restrict__ sse){
  __shared__ float g[15];
  __shared__ float t[2];
  int b = blockIdx.x, l = threadIdx.x;
  for (int c = 0; c < 15; ++c){
    float p = 0.f;
    for (int k = l; k < 196; k += 64) p += y[((size_t)b*15 + c)*196 + k];
    p += __shfl_xor(p, 32); p += __shfl_xor(p, 16); p += __shfl_xor(p, 8);
    p += __shfl_xor(p, 4);  p += __shfl_xor(p, 2);  p += __shfl_xor(p, 1);
    if (l == 0) g[c] = p * (1.f/196.f);
  }
  __syncthreads();
  if (l < 2){
    float a = 0.f;
    for (int c = 0; c < 15; ++c) a += g[c] * fc1[l*15 + c];
    t[l] = fmaxf(a, 0.f);
  }
  __syncthreads();
  if (l < 15){
    float h = t[0]*fc2[l*2] + t[1]*fc2[l*2+1];
    sse[b*15 + l] = 1.f / (1.f + __expf(-h));
  }
}

// ---------------- weights -> bf16 (pw1 K-padded to 1600 with zeros) ----------------
__global__ void wconv_kernel(const float* __restrict__ cw, const float* __restrict__ pw,
                             u16* __restrict__ wbz, u16* __restrict__ wbp){
  u32 stride = gridDim.x * blockDim.x;
  for (u32 i = blockIdx.x*blockDim.x + threadIdx.x; i < 524288u; i += stride)
    wbz[i] = f2bf(cw[i]);
  for (u32 i = blockIdx.x*blockDim.x + threadIdx.x; i < 819200u; i += stride){
    u32 n = i / 1600u, k = i - n*1600u;
    wbp[i] = f2bf(k < 1551u ? pw[(size_t)n*1551 + k] : 0.f);
  }
}

// ---------------- cov v7: 64 ch/block; TRIANGULAR covT'; EARLY prefetch issue ---------
__global__ __launch_bounds__(256,2) void cov_kernel(const float* __restrict__ x,
    const float* __restrict__ dcw, const float* __restrict__ dcb, u16* __restrict__ covT){
  __shared__ __align__(16) float xs[2*3136];       // 2 x [16ch][196] f32 = 25,088 B
  __shared__ __align__(16) u32 xcb[16*132];        // [c][16 rows][8 u32] + pad, 8,448 B
  __shared__ __align__(16) u32 covL32[32*210];     // [cpair][210], 26,880 B
  __shared__ float wls[64][9];
  __shared__ float wlb[64];
  __shared__ u16 tij[112];                         // t -> ij (=i*14+j, i<=j)

  int tid = threadIdx.x;
  int c0 = blockIdx.x * 64, b = blockIdx.y;
  const float* xbase = x + ((size_t)b*1024 + c0)*196;

  #pragma unroll
  for (int i = 0; i < 3; ++i){
    int s = tid + i*256;
    GLDS16(xbase + s*4, xs + s*4);
  }
  if (tid < 16){ int s = tid + 768; GLDS16(xbase + s*4, xs + s*4); }

  for (int i = tid; i < 576; i += 256) wls[i/9][i%9] = dcw[(size_t)(c0 + i/9)*9 + (i%9)];
  if (tid < 64) wlb[tid] = dcb[c0 + tid];
  if (tid < 196){
    int ii = tid / 14, jj = tid - ii*14;
    if (ii <= jj){
      int t = 13*ii - (ii*(ii-1))/2 + jj;
      tij[t] = (u16)tid;
    }
  }

  for (int sg = 0; sg < 4; ++sg){
    u32 xo = (u32)(sg & 1) * 3136u;
    asm volatile("s_waitcnt vmcnt(0)" ::: "memory");
    __builtin_amdgcn_s_barrier();                      // every wave's tile landed; xcb free
    asm volatile("" ::: "memory");

    if (sg < 3){                                       // EARLY prefetch: overlaps conv+MFMA
      const float* nsrc = xbase + (size_t)(sg+1)*3136;
      u32 xo2 = xo ^ 3136u;
      #pragma unroll
      for (int i = 0; i < 3; ++i){
        int s = tid + i*256;
        GLDS16(nsrc + s*4, xs + xo2 + s*4);
      }
      if (tid < 16){ int s = tid + 768; GLDS16(nsrc + s*4, xs + xo2 + s*4); }
    }

    { // conv + row-center + bf16 pack; one thread = one (c, out-row)
      int c = tid >> 4, i = tid & 15;
      int cg = sg*16 + c;
      u32 q[8];
      #pragma unroll
      for (int j = 0; j < 8; ++j) q[j] = 0u;
      if (i < 14){
        float wr[9];
        #pragma unroll
        for (int qq = 0; qq < 9; ++qq) wr[qq] = wls[cg][qq];
        float topm = (i > 0) ? 1.f : 0.f, botm = (i < 13) ? 1.f : 0.f;
        wr[0] *= topm; wr[1] *= topm; wr[2] *= topm;
        wr[6] *= botm; wr[7] *= botm; wr[8] *= botm;
        float bb = wlb[cg];
        float rr[3][16];
        #pragma unroll
        for (int d = 0; d < 3; ++d){
          rr[d][0] = 0.f; rr[d][15] = 0.f;
          int rowr = i + d - 1;
          rowr = rowr < 0 ? 0 : (rowr > 13 ? 13 : rowr);
          const float* src = &xs[xo + c*196 + rowr*14];
          #pragma unroll
          for (int j = 0; j < 7; ++j)
            *(float2*)&rr[d][1 + 2*j] = *(const float2*)&src[2*j];
        }
        float ov[14];
        #pragma unroll
        for (int k = 0; k < 14; ++k){
          float a = bb;
          #pragma unroll
          for (int dy = 0; dy < 3; ++dy)
            #pragma unroll
            for (int dx = 0; dx < 3; ++dx)
              a += wr[dy*3+dx] * rr[dy][k + dx];
          ov[k] = a;
        }
        float mean = 0.f;
        #pragma unroll
        for (int k = 0; k < 14; ++k) mean += ov[k];
        mean *= (1.f/14.f);
        #pragma unroll
        for (int j = 0; j < 7; ++j)
          q[j] = pk2bf(ov[2*j] - mean, ov[2*j+1] - mean);
      }
      u32x4 q0 = {q[0], q[1], q[2], q[3]};
      u32x4 q1 = {q[4], q[5], q[6], q[7]};
      *(u32x4*)&xcb[c*132 + i*8]     = q0;
      *(u32x4*)&xcb[c*132 + i*8 + 4] = q1;
    }
    __builtin_amdgcn_s_barrier();                    // xcb ready

    { // cov = xc * xc^T / 13 for these 16 ch; cpair = sg*8 + w*2 + pp
      int w = tid >> 6, l = tid & 63, lr = l & 15, lq = l >> 4;
      #pragma unroll
      for (int pp = 0; pp < 2; ++pp){
        int clo = w*4 + 2*pp;
        bf16x8 alo = {0,0,0,0,0,0,0,0}, ahi = {0,0,0,0,0,0,0,0};
        if (lq < 2){
          alo = *(const bf16x8*)&xcb[clo*132 + lr*8 + lq*4];
          ahi = *(const bf16x8*)&xcb[(clo+1)*132 + lr*8 + lq*4];
        }
        f32x4 dlo = {0.f,0.f,0.f,0.f}, dhi = {0.f,0.f,0.f,0.f};
        dlo = __builtin_amdgcn_mfma_f32_16x16x32_bf16(alo, alo, dlo, 0, 0, 0);
        dhi = __builtin_amdgcn_mfma_f32_16x16x32_bf16(ahi, ahi, dhi, 0, 0, 0);
        if (lr < 14){
          int cp = sg*8 + w*2 + pp;
          #pragma unroll
          for (int r = 0; r < 4; ++r){
            int rowi = lq*4 + r;   // D: row=(lane>>4)*4+reg, col=lane&15
            if (rowi < 14){
              u32 vv = pk2bf(dlo[r] * (1.f/13.f), dhi[r] * (1.f/13.f));
              covL32[cp*210 + rowi*14 + lr] = vv;
            }
          }
        }
      }
    }
  }
  __syncthreads();

  for (int i = tid; i < 840; i += 256){   // triangular writeout: 8 lanes x 16B = 128B/(b,t)
    int g = i & 7, t = i >> 3;
    int ij = tij[t];
    u32x4 v;
    v.x = covL32[(g*4+0)*210 + ij];
    v.y = covL32[(g*4+1)*210 + ij];
    v.z = covL32[(g*4+2)*210 + ij];
    v.w = covL32[(g*4+3)*210 + ij];
    *(u32x4*)(covT + ((size_t)(b*105 + t)*1024 + c0 + g*8)) = v;
  }
}

// ---------------- zsig: in-place sigmoid(bn(z)) on triangular zT [512][26880] bf16 ----
__global__ void zsig_kernel(u32* __restrict__ zt, const float* __restrict__ scz,
                            const float* __restrict__ shz){
  u32 stride = gridDim.x * blockDim.x;
  for (u32 i = blockIdx.x*blockDim.x + threadIdx.x; i < 6881280u; i += stride){
    u32 o = i / 13440u;                    // 26880/2 u32 per row
    float s = scz[o], h = shz[o];
    u32 v = zt[i];
    float v0 = bf2f((u16)(v & 0xffffu)) * s + h;
    float v1 = bf2f((u16)(v >> 16))     * s + h;
    v0 = 1.f / (1.f + __expf(-v0));
    v1 = 1.f / (1.f + __expf(-v1));
    zt[i] = pk2bf(v0, v1);
  }
}

// ---------------- build Adw[(b*196+ij)*1600+cc] = dw3x3(cat)[cc] bf16 ----------------
__global__ __launch_bounds__(256,5) void adw_kernel(
    const float* __restrict__ y, const float* __restrict__ sse,
    const u16* __restrict__ zT,
    const float* __restrict__ x, const float* __restrict__ dw1w, const float* __restrict__ dw1b,
    u16* __restrict__ Adw){
  __shared__ __align__(16) float ms[32*202];       // 25,856 B
  __shared__ float wd[32][9];
  __shared__ float bd[32];
  __shared__ u16 ttab[196];                        // p=(i,j) -> triangular t
  int tid = threadIdx.x;
  int cc0 = blockIdx.x * 32, b = blockIdx.y;

  if (tid < 196){
    int ii = tid / 14, jj = tid - ii*14;
    int im = ii < jj ? ii : jj, jm = ii < jj ? jj : ii;
    ttab[tid] = (u16)(13*im - (im*(im-1))/2 + jm);
  }
  __syncthreads();                                 // ttab ready before z staging

  for (int i = tid; i < 288; i += 256){
    int c = i / 9, q = i - c*9;
    int cc = cc0 + c;
    wd[c][q] = (cc < 1551) ? dw1w[(size_t)cc*9 + q] : 0.f;
  }
  if (tid < 32) bd[tid] = (cc0 + tid < 1551) ? dw1b[cc0 + tid] : 0.f;

  if (cc0 < 15){                                   // y1 channels [0,15) (chunk 0 only)
    int ny = 15;
    for (int i = tid; i < ny*196; i += 256){
      u32 c = (u32)i / 196u, p = (u32)i - c*196u;
      ms[c*202u + p] = y[((size_t)b*15 + c)*196 + p] * sse[b*15 + c];
    }
  }
  {                                                // z channels [15,527): pure gather
    int zs = cc0 > 15 ? cc0 : 15;
    int ze = cc0 + 32 < 527 ? cc0 + 32 : 527;
    if (zs < ze){
      int nz = ze - zs, lbase = zs - cc0, obase = zs - 15;
      const u16* zb = zT + (size_t)obase*26880 + (size_t)b*105;
      for (int i = tid; i < nz*196; i += 256){
        u32 oo = (u32)i / 196u, p = (u32)i - oo*196u;
        ms[(u32)(lbase + (int)oo)*202u + p] = bf2f(zb[(size_t)oo*26880 + ttab[p]]);
      }
    }
  }
  {                                                // x channels [527,1551): float4 loads
    int xs_ = cc0 > 527 ? cc0 : 527;
    int xe = cc0 + 32 < 1551 ? cc0 + 32 : 1551;
    if (xs_ < xe){
      int nx = xe - xs_, lbase = xs_ - cc0, cxs = xs_ - 527;
      const float4* xg = (const float4*)(x + ((size_t)b*1024 + cxs)*196);
      for (int i = tid; i < nx*49; i += 256){
        float4 v = xg[i];
        u32 c = (u32)i / 49u, p4 = (u32)i - c*49u;
        float* dst = &ms[(u32)(lbase + (int)c)*202u + p4*4u];
        float2 lo = {v.x, v.y}, hi = {v.z, v.w};
        *(float2*)dst = lo;
        *(float2*)(dst + 2) = hi;
      }
    }
  }
  {                                                // K pad [1551,1600) -> zeros
    int ps = cc0 > 1551 ? cc0 : 1551;
    int pe = cc0 + 32;
    if (ps < pe){
      int np = pe - ps, lbase = ps - cc0;
      for (int i = tid; i < np*196; i += 256){
        u32 c = (u32)i / 196u, p = (u32)i - c*196u;
        ms[(u32)(lbase + (int)c)*202u + p] = 0.f;
      }
    }
  }
  __syncthreads();

  for (int t = tid; t < 448; t += 256){            // conv: one thread = one (cc, out-row)
    int cc = t & 31, i = t >> 5;                   // lanes along cc -> coalesced stores
    float wr[9];
    #pragma unroll
    for (int qq = 0; qq < 9; ++qq) wr[qq] = wd[cc][qq];
    float topm = (i > 0) ? 1.f : 0.f, botm = (i < 13) ? 1.f : 0.f;
    wr[0] *= topm; wr[1] *= topm; wr[2] *= topm;
    wr[6] *= botm; wr[7] *= botm; wr[8] *= botm;
    float bb = bd[cc];
    float rr[3][16];
    #pragma unroll
    for (int d = 0; d < 3; ++d){
      rr[d][0] = 0.f; rr[d][15] = 0.f;
      int rowr = i + d - 1;
      rowr = rowr < 0 ? 0 : (rowr > 13 ? 13 : rowr);
      const float* src = &ms[cc*202 + rowr*14];
      #pragma unroll
      for (int j = 0; j < 7; ++j)
        *(float2*)&rr[d][1 + 2*j] = *(const float2*)&src[2*j];
    }
    size_t obase = ((size_t)b*196 + i*14) * 1600 + cc0 + cc;
    #pragma unroll
    for (int k = 0; k < 14; ++k){
      float a = bb;
      #pragma unroll
      for (int dy = 0; dy < 3; ++dy)
        #pragma unroll
        for (int dx = 0; dx < 3; ++dx)
          a += wr[dy*3+dx] * rr[dy][k + dx];
      Adw[obase + (size_t)k*1600] = f2bf(a);
    }
  }
}

// ---------------- NT GEMM v6: 128x128, BK=32, dbuf + counted vmcnt -> 4 blocks/CU ----
// LDS = max(2x(A8K+B8K)=32KB, epilogue 33.28KB) = 33.28KB -> occupancy 4 (was 2 @ BK=64).
// Per K-step each wave issues 4 global_load_lds; vmcnt(4) keeps prefetch in flight.
// Frag col group q = lq ^ (row&3); stage swizzle sc = (s&3) ^ (row&3).
// MODE 0 (z): M'=26880 triangular; per-thread weighted BN stats (1 diag / 2 off-diag).
// MODE 1 (o): M=50176, f32 NCHW-transposed. XCD swizzle lin=(g&7)*per+(g>>3).
template<int MODE>
__global__ __launch_bounds__(256,4) void gemm_kernel(
    const u16* __restrict__ A, const u16* __restrict__ Bw,
    const float* __restrict__ bias, void* __restrict__ outp,
    float* __restrict__ stats, int K){
  __shared__ __align__(16) u16 lds[16640];         // 33,280 B

  int tid = threadIdx.x;
  int w = tid >> 6, l = tid & 63;
  int wm = w >> 1, wn = w & 1;
  int lr = l & 15, lq = l >> 4;
  u32 g = blockIdx.x;
  u32 per = gridDim.x >> 3;
  u32 lin = (g & 7u) * per + (g >> 3);
  int n0 = (int)(lin & 3u) * 128;
  int m0 = (int)(lin >> 2) * 128;

  f32x4 acc[4][4] = {};
  int kTiles = K >> 5;

  const u16* Abase = A  + (size_t)m0*K;
  const u16* Bbase = Bw + (size_t)n0*K;

  // prologue: stage tile 0 into buf 0 (512 slots x 16B each matrix)
  #pragma unroll
  for (int i = 0; i < 2; ++i){
    int s = tid + i*256;
    int row = s >> 2, c4 = s & 3, sc = c4 ^ (row & 3);
    GLDS16(Abase + (size_t)row*K + sc*8, lds + s*8);
    GLDS16(Bbase + (size_t)row*K + sc*8, lds + 4096 + s*8);
  }

  for (int kt = 0; kt < kTiles; ++kt){
    u32 bufo = (u32)(kt & 1) * 8192u;
    if (kt > 0) __builtin_amdgcn_s_barrier();      // all waves done computing on buf^1
    if (kt + 1 < kTiles){                          // prefetch next tile into other buffer
      u32 nbufo = bufo ^ 8192u;
      #pragma unroll
      for (int i = 0; i < 2; ++i){
        int s = tid + i*256;
        int row = s >> 2, c4 = s & 3, sc = c4 ^ (row & 3);
        GLDS16(Abase + (size_t)row*K + (kt+1)*32 + sc*8, lds + nbufo + s*8);
        GLDS16(Bbase + (size_t)row*K + (kt+1)*32 + sc*8, lds + nbufo + 4096 + s*8);
      }
      asm volatile("s_waitcnt vmcnt(4)" ::: "memory");   // tile kt landed; prefetch in flight
    } else {
      asm volatile("s_waitcnt vmcnt(0)" ::: "memory");
    }
    __builtin_amdgcn_s_barrier();                  // every wave's tile-kt loads landed
    asm volatile("" ::: "memory");                 // no ds_read hoists above the barrier
    const u16* Ac = lds + bufo;
    const u16* Bc = lds + bufo + 4096;
    bf16x8 af[4], bfv[4];
    #pragma unroll
    for (int mi = 0; mi < 4; ++mi){
      int row = wm*64 + mi*16 + lr;
      int q = lq ^ (row & 3);
      af[mi] = *(const bf16x8*)(Ac + row*32 + q*8);
    }
    #pragma unroll
    for (int ni = 0; ni < 4; ++ni){
      int row = wn*64 + ni*16 + lr;
      int q = lq ^ (row & 3);
      bfv[ni] = *(const bf16x8*)(Bc + row*32 + q*8);
    }
    __builtin_amdgcn_s_setprio(1);
    #pragma unroll
    for (int mi = 0; mi < 4; ++mi)
      #pragma unroll
      for (int ni = 0; ni < 4; ++ni)
        acc[mi][ni] = __builtin_amdgcn_mfma_f32_16x16x32_bf16(af[mi], bfv[ni], acc[mi][ni], 0, 0, 0);
    __builtin_amdgcn_s_setprio(0);
  }
  __syncthreads();                                 // all compute done before LDS reuse

  // row weights for triangular mode (1 diag, 2 off-diag), computed per-thread
  float wgt16[4][4];
  if (MODE == 0){
    #pragma unroll
    for (int mi = 0; mi < 4; ++mi)
      #pragma unroll
      for (int r = 0; r < 4; ++r){
        int rowm = m0 + wm*64 + mi*16 + lq*4 + r;
        u32 t = (u32)rowm % 105u;
        float wgt = 2.f;
        #pragma unroll
        for (int ii = 0; ii < 14; ++ii){
          int td = 14*ii - (ii*(ii-1))/2;
          if ((int)t == td) wgt = 1.f;
        }
        wgt16[mi][r] = wgt;
      }
  }

  // bias + per-column BN stats (sum, sumsq)
  #pragma unroll
  for (int ni = 0; ni < 4; ++ni){
    int col = n0 + wn*64 + ni*16 + lr;
    float bb = bias[col];
    float s1 = 0.f, s2 = 0.f;
    #pragma unroll
    for (int mi = 0; mi < 4; ++mi)
      #pragma unroll
      for (int r = 0; r < 4; ++r){
        float v = acc[mi][ni][r] + bb;
        acc[mi][ni][r] = v;
        float wv = (MODE == 0) ? wgt16[mi][r] : 1.f;
        s1 += wv*v; s2 += wv*v*v;
      }
    s1 += __shfl_xor(s1, 16); s1 += __shfl_xor(s1, 32);
    s2 += __shfl_xor(s2, 16); s2 += __shfl_xor(s2, 32);
    if (lq == 0){
      atomicAdd(&stats[col], s1);
      atomicAdd(&stats[512 + col], s2);
    }
  }

  float* eb = (float*)lds;                         // 2 x [64][65] f32 = 33,280 B exact
  #pragma unroll
  for (int rnd = 0; rnd < 2; ++rnd){
    if (wm == rnd){
      float* e = eb + wn * (64*65);
      #pragma unroll
      for (int mi = 0; mi < 4; ++mi)
        #pragma unroll
        for (int ni = 0; ni < 4; ++ni)
          #pragma unroll
          for (int r = 0; r < 4; ++r)
            e[(mi*16 + lq*4 + r)*65 + ni*16 + lr] = acc[mi][ni][r];
      int m = m0 + wm*64 + l;
      if (MODE == 0){
        u16* ob = (u16*)outp + (size_t)(n0 + wn*64)*26880 + m;
        #pragma unroll 8
        for (int no = 0; no < 64; ++no)
          ob[(size_t)no*26880] = f2bf(e[l*65 + no]);
      } else {
        u32 bq = (u32)m / 196u;
        u32 ij = (u32)m - bq*196u;
        float* ob = (float*)outp + ((size_t)bq*512 + n0 + wn*64)*196 + ij;
        #pragma unroll 8
        for (int no = 0; no < 64; ++no)
          ob[(size_t)no*196] = e[l*65 + no];
      }
    }
    __syncthreads();
  }
}

// ---------------- BN prep: stats -> scale/shift ----------------
__global__ void bnprep_kernel(const float* __restrict__ stats, const float* __restrict__ gamma,
    const float* __restrict__ beta, float* __restrict__ sc, float* __restrict__ sh){
  int o = threadIdx.x;
  float m = stats[o] * (1.f/50176.f);
  float v = stats[512+o] * (1.f/50176.f) - m*m;
  float inv = rsqrtf(v + EPSBN);
  float g = gamma[o] * inv;
  sc[o] = g;
  sh[o] = beta[o] - m*g;
}

// ---------------- final: relu(bn(o)) in place on d_out (NCHW) ----------------
__global__ void final_kernel(float4* __restrict__ o4, const float* __restrict__ sc,
                             const float* __restrict__ sh){
  u32 stride = gridDim.x * blockDim.x;
  for (u32 i = blockIdx.x*blockDim.x + threadIdx.x; i < 6422528u; i += stride){
    u32 oc = (i / 49u) & 511u;
    float s = sc[oc], t = sh[oc];
    float4 v = o4[i];
    v.x = fmaxf(fmaf(v.x, s, t), 0.f);
    v.y = fmaxf(fmaf(v.y, s, t), 0.f);
    v.z = fmaxf(fmaf(v.z, s, t), 0.f);
    v.w = fmaxf(fmaf(v.w, s, t), 0.f);
    o4[i] = v;
  }
}

extern "C" void kernel_launch(void* const* d_in, const int* in_sizes, int n_in,
                              void* d_out, int out_size, void* d_ws, size_t ws_size,
                              hipStream_t stream){
  (void)in_sizes; (void)n_in; (void)out_size; (void)ws_size;
  const float* y      = (const float*)d_in[0];
  const float* x      = (const float*)d_in[1];
  const float* fc1    = (const float*)d_in[2];
  const float* fc2    = (const float*)d_in[3];
  const float* convw  = (const float*)d_in[4];
  const float* convb  = (const float*)d_in[5];
  const float* dconvw = (const float*)d_in[6];
  const float* dconvb = (const float*)d_in[7];
  const float* dw1w   = (const float*)d_in[8];
  const float* dw1b   = (const float*)d_in[9];
  const float* pw1w   = (const float*)d_in[10];
  const float* pw1b   = (const float*)d_in[11];
  const float* gamma  = (const float*)d_in[12];
  const float* beta   = (const float*)d_in[13];

  char* ws = (char*)d_ws;
  u16* covT   = (u16*)(ws + OFF_COVT);
  u16* Adw    = (u16*)(ws + OFF_ADW);
  float* sse  = (float*)(ws + OFF_S);
  u16* wbz    = (u16*)(ws + OFF_WBZ);
  u16* wbp    = (u16*)(ws + OFF_WBP);
  float* statsZ = (float*)(ws + OFF_STATSZ);
  float* statsO = (float*)(ws + OFF_STATSO);
  float* scz  = (float*)(ws + OFF_SCZ);
  float* shz  = (float*)(ws + OFF_SHZ);
  float* sco  = (float*)(ws + OFF_SCO);
  float* sho  = (float*)(ws + OFF_SHO);
  u16* zT     = (u16*)d_out;      // triangular z [512][26880] bf16 in d_out, dead before o written
  float* outf = (float*)d_out;

  hipMemsetAsync(statsZ, 0, 8192, stream);
  se_kernel<<<256, 64, 0, stream>>>(y, fc1, fc2, sse);
  wconv_kernel<<<2048, 256, 0, stream>>>(convw, pw1w, wbz, wbp);
  cov_kernel<<<dim3(16, 256), 256, 0, stream>>>(x, dconvw, dconvb, covT);
  gemm_kernel<0><<<840, 256, 0, stream>>>(covT, wbz, convb, (void*)zT, statsZ, 1024);
  bnprep_kernel<<<1, 512, 0, stream>>>(statsZ, gamma, beta, scz, shz);
  zsig_kernel<<<2048, 256, 0, stream>>>((u32*)zT, scz, shz);
  adw_kernel<<<dim3(50, 256), 256, 0, stream>>>(y, sse, zT, x, dw1w, dw1b, Adw);
  gemm_kernel<1><<<1568, 256, 0, stream>>>(Adw, wbp, pw1b, (void*)outf, statsO, 1600);
  bnprep_kernel<<<1, 512, 0, stream>>>(statsO, gamma, beta, sco, sho);
  final_kernel<<<8192, 256, 0, stream>>>((float4*)outf, sco, sho);
}

// Round 19
// 445.723 us; speedup vs baseline: 1.0594x; 1.0594x over previous
//
#include <hip/hip_runtime.h>

typedef unsigned int u32;
typedef unsigned short u16;
typedef __attribute__((ext_vector_type(8))) short bf16x8;
typedef __attribute__((ext_vector_type(4))) float f32x4;
typedef __attribute__((ext_vector_type(4))) u32 u32x4;

// ---- problem constants ----
// B=256, C=1024, S=14, SS=196, C2=15, NCH=512, CAT=1551 (pad->1600), M=50176
// Triangular spatial: T=105 unique (i<=j) pairs; M' = 256*105 = 26,880
#define EPSBN 1e-5f

// async global->LDS, 16B per lane; LDS dest = wave-uniform base + lane*16 (linear in s)
#define GLDS16(gp, lp) __builtin_amdgcn_global_load_lds( \
    (const __attribute__((address_space(1))) u32*)(gp), \
    (__attribute__((address_space(3))) u32*)(lp), 16, 0, 0)

// ---- ws offsets (bytes) ----
#define OFF_ADW    0ull           // 50176*1600*2 = 160,563,200  (Adw bf16, K-padded)
#define OFF_COVT   0ull           // 26880*1024*2 = 55,050,240 (aliases Adw; dead before Adw written)
#define OFF_S      160563200ull   // 256*15*4
#define OFF_WBZ    160578560ull   // 512*1024*2 bf16 conv_w
#define OFF_WBP    161627136ull   // 512*1600*2 bf16 pw1_w padded
#define OFF_STATSZ 163265536ull   // 1024 f32 (sum,sumsq)
#define OFF_STATSO 163269632ull
#define OFF_SCZ    163273728ull
#define OFF_SHZ    163275776ull
#define OFF_SCO    163277824ull
#define OFF_SHO    163279872ull

static __device__ __forceinline__ float bf2f(u16 h){
  u32 u = ((u32)h) << 16; float f; __builtin_memcpy(&f, &u, 4); return f;
}
static __device__ __forceinline__ u16 f2bf(float f){
  u32 u; __builtin_memcpy(&u, &f, 4);
  u = (u + 0x7fffu + ((u >> 16) & 1u)) >> 16;
  return (u16)u;
}
// packed 2xf32 -> 2xbf16 (RNE) in ONE VALU op; no builtin on gfx950 -> inline asm (T12)
static __device__ __forceinline__ u32 pk2bf(float lo, float hi){
  u32 r;
  asm("v_cvt_pk_bf16_f32 %0, %1, %2" : "=v"(r) : "v"(lo), "v"(hi));
  return r;
}

// ---------------- SE block: s[b][15] = sigmoid(relu(g@fc1^T)@fc2^T) ----------------
__global__ __launch_bounds__(64) void se_kernel(const float* __restrict__ y,
    const float* __restrict__ fc1, const float* __restrict__ fc2, float* __restrict__ sse){
  __shared__ float g[15];
  __shared__ float t[2];
  int b = blockIdx.x, l = threadIdx.x;
  for (int c = 0; c < 15; ++c){
    float p = 0.f;
    for (int k = l; k < 196; k += 64) p += y[((size_t)b*15 + c)*196 + k];
    p += __shfl_xor(p, 32); p += __shfl_xor(p, 16); p += __shfl_xor(p, 8);
    p += __shfl_xor(p, 4);  p += __shfl_xor(p, 2);  p += __shfl_xor(p, 1);
    if (l == 0) g[c] = p * (1.f/196.f);
  }
  __syncthreads();
  if (l < 2){
    float a = 0.f;
    for (int c = 0; c < 15; ++c) a += g[c] * fc1[l*15 + c];
    t[l] = fmaxf(a, 0.f);
  }
  __syncthreads();
  if (l < 15){
    float h = t[0]*fc2[l*2] + t[1]*fc2[l*2+1];
    sse[b*15 + l] = 1.f / (1.f + __expf(-h));
  }
}

// ---------------- weights -> bf16 (pw1 K-padded to 1600 with zeros) ----------------
__global__ void wconv_kernel(const float* __restrict__ cw, const float* __restrict__ pw,
                             u16* __restrict__ wbz, u16* __restrict__ wbp){
  u32 stride = gridDim.x * blockDim.x;
  for (u32 i = blockIdx.x*blockDim.x + threadIdx.x; i < 524288u; i += stride)
    wbz[i] = f2bf(cw[i]);
  for (u32 i = blockIdx.x*blockDim.x + threadIdx.x; i < 819200u; i += stride){
    u32 n = i / 1600u, k = i - n*1600u;
    wbp[i] = f2bf(k < 1551u ? pw[(size_t)n*1551 + k] : 0.f);
  }
}

// ---------------- cov v8: TRIANGULAR covL (105 entries/cpair) -> 50.4KB LDS, 3 blk/CU --
// MFMA epilogue stores only i<=j (each t written once); early prefetch retained.
__global__ __launch_bounds__(256,3) void cov_kernel(const float* __restrict__ x,
    const float* __restrict__ dcw, const float* __restrict__ dcb, u16* __restrict__ covT){
  __shared__ __align__(16) float xs[2*3136];       // 2 x [16ch][196] f32 = 25,088 B
  __shared__ __align__(16) u32 xcb[16*132];        // [c][16 rows][8 u32] + pad, 8,448 B
  __shared__ __align__(16) u32 covL32[32*112];     // [cpair][112] triangular, 14,336 B
  __shared__ float wls[64][9];
  __shared__ float wlb[64];

  int tid = threadIdx.x;
  int c0 = blockIdx.x * 64, b = blockIdx.y;
  const float* xbase = x + ((size_t)b*1024 + c0)*196;

  #pragma unroll
  for (int i = 0; i < 3; ++i){
    int s = tid + i*256;
    GLDS16(xbase + s*4, xs + s*4);
  }
  if (tid < 16){ int s = tid + 768; GLDS16(xbase + s*4, xs + s*4); }

  for (int i = tid; i < 576; i += 256) wls[i/9][i%9] = dcw[(size_t)(c0 + i/9)*9 + (i%9)];
  if (tid < 64) wlb[tid] = dcb[c0 + tid];

  for (int sg = 0; sg < 4; ++sg){
    u32 xo = (u32)(sg & 1) * 3136u;
    asm volatile("s_waitcnt vmcnt(0)" ::: "memory");
    __builtin_amdgcn_s_barrier();                      // every wave's tile landed; xcb free
    asm volatile("" ::: "memory");

    if (sg < 3){                                       // EARLY prefetch: overlaps conv+MFMA
      const float* nsrc = xbase + (size_t)(sg+1)*3136;
      u32 xo2 = xo ^ 3136u;
      #pragma unroll
      for (int i = 0; i < 3; ++i){
        int s = tid + i*256;
        GLDS16(nsrc + s*4, xs + xo2 + s*4);
      }
      if (tid < 16){ int s = tid + 768; GLDS16(nsrc + s*4, xs + xo2 + s*4); }
    }

    { // conv + row-center + bf16 pack; one thread = one (c, out-row)
      int c = tid >> 4, i = tid & 15;
      int cg = sg*16 + c;
      u32 q[8];
      #pragma unroll
      for (int j = 0; j < 8; ++j) q[j] = 0u;
      if (i < 14){
        float wr[9];
        #pragma unroll
        for (int qq = 0; qq < 9; ++qq) wr[qq] = wls[cg][qq];
        float topm = (i > 0) ? 1.f : 0.f, botm = (i < 13) ? 1.f : 0.f;
        wr[0] *= topm; wr[1] *= topm; wr[2] *= topm;
        wr[6] *= botm; wr[7] *= botm; wr[8] *= botm;
        float bb = wlb[cg];
        float rr[3][16];
        #pragma unroll
        for (int d = 0; d < 3; ++d){
          rr[d][0] = 0.f; rr[d][15] = 0.f;
          int rowr = i + d - 1;
          rowr = rowr < 0 ? 0 : (rowr > 13 ? 13 : rowr);
          const float* src = &xs[xo + c*196 + rowr*14];
          #pragma unroll
          for (int j = 0; j < 7; ++j)
            *(float2*)&rr[d][1 + 2*j] = *(const float2*)&src[2*j];
        }
        float ov[14];
        #pragma unroll
        for (int k = 0; k < 14; ++k){
          float a = bb;
          #pragma unroll
          for (int dy = 0; dy < 3; ++dy)
            #pragma unroll
            for (int dx = 0; dx < 3; ++dx)
              a += wr[dy*3+dx] * rr[dy][k + dx];
          ov[k] = a;
        }
        float mean = 0.f;
        #pragma unroll
        for (int k = 0; k < 14; ++k) mean += ov[k];
        mean *= (1.f/14.f);
        #pragma unroll
        for (int j = 0; j < 7; ++j)
          q[j] = pk2bf(ov[2*j] - mean, ov[2*j+1] - mean);
      }
      u32x4 q0 = {q[0], q[1], q[2], q[3]};
      u32x4 q1 = {q[4], q[5], q[6], q[7]};
      *(u32x4*)&xcb[c*132 + i*8]     = q0;
      *(u32x4*)&xcb[c*132 + i*8 + 4] = q1;
    }
    __builtin_amdgcn_s_barrier();                    // xcb ready

    { // cov = xc * xc^T / 13 for these 16 ch; triangular store (i<=j only)
      int w = tid >> 6, l = tid & 63, lr = l & 15, lq = l >> 4;
      #pragma unroll
      for (int pp = 0; pp < 2; ++pp){
        int clo = w*4 + 2*pp;
        bf16x8 alo = {0,0,0,0,0,0,0,0}, ahi = {0,0,0,0,0,0,0,0};
        if (lq < 2){
          alo = *(const bf16x8*)&xcb[clo*132 + lr*8 + lq*4];
          ahi = *(const bf16x8*)&xcb[(clo+1)*132 + lr*8 + lq*4];
        }
        f32x4 dlo = {0.f,0.f,0.f,0.f}, dhi = {0.f,0.f,0.f,0.f};
        dlo = __builtin_amdgcn_mfma_f32_16x16x32_bf16(alo, alo, dlo, 0, 0, 0);
        dhi = __builtin_amdgcn_mfma_f32_16x16x32_bf16(ahi, ahi, dhi, 0, 0, 0);
        if (lr < 14){
          int cp = sg*8 + w*2 + pp;
          #pragma unroll
          for (int r = 0; r < 4; ++r){
            int rowi = lq*4 + r;   // D: row=(lane>>4)*4+reg, col=lane&15
            if (rowi < 14 && rowi <= lr){
              int t = 13*rowi - (rowi*(rowi-1))/2 + lr;
              u32 vv = pk2bf(dlo[r] * (1.f/13.f), dhi[r] * (1.f/13.f));
              covL32[cp*112 + t] = vv;
            }
          }
        }
      }
    }
  }
  __syncthreads();

  for (int i = tid; i < 840; i += 256){   // triangular writeout: 8 lanes x 16B = 128B/(b,t)
    int g = i & 7, t = i >> 3;
    u32x4 v;
    v.x = covL32[(g*4+0)*112 + t];
    v.y = covL32[(g*4+1)*112 + t];
    v.z = covL32[(g*4+2)*112 + t];
    v.w = covL32[(g*4+3)*112 + t];
    *(u32x4*)(covT + ((size_t)(b*105 + t)*1024 + c0 + g*8)) = v;
  }
}

// ---------------- zsig: in-place sigmoid(bn(z)) on triangular zT [512][26880] bf16 ----
__global__ void zsig_kernel(u32* __restrict__ zt, const float* __restrict__ scz,
                            const float* __restrict__ shz){
  u32 stride = gridDim.x * blockDim.x;
  for (u32 i = blockIdx.x*blockDim.x + threadIdx.x; i < 6881280u; i += stride){
    u32 o = i / 13440u;                    // 26880/2 u32 per row
    float s = scz[o], h = shz[o];
    u32 v = zt[i];
    float v0 = bf2f((u16)(v & 0xffffu)) * s + h;
    float v1 = bf2f((u16)(v >> 16))     * s + h;
    v0 = 1.f / (1.f + __expf(-v0));
    v1 = 1.f / (1.f + __expf(-v1));
    zt[i] = pk2bf(v0, v1);
  }
}

// ---------------- build Adw[(b*196+ij)*1600+cc] = dw3x3(cat)[cc] bf16 ----------------
__global__ __launch_bounds__(256,5) void adw_kernel(
    const float* __restrict__ y, const float* __restrict__ sse,
    const u16* __restrict__ zT,
    const float* __restrict__ x, const float* __restrict__ dw1w, const float* __restrict__ dw1b,
    u16* __restrict__ Adw){
  __shared__ __align__(16) float ms[32*202];       // 25,856 B
  __shared__ float wd[32][9];
  __shared__ float bd[32];
  __shared__ u16 ttab[196];                        // p=(i,j) -> triangular t
  int tid = threadIdx.x;
  int cc0 = blockIdx.x * 32, b = blockIdx.y;

  if (tid < 196){
    int ii = tid / 14, jj = tid - ii*14;
    int im = ii < jj ? ii : jj, jm = ii < jj ? jj : ii;
    ttab[tid] = (u16)(13*im - (im*(im-1))/2 + jm);
  }
  __syncthreads();                                 // ttab ready before z staging

  for (int i = tid; i < 288; i += 256){
    int c = i / 9, q = i - c*9;
    int cc = cc0 + c;
    wd[c][q] = (cc < 1551) ? dw1w[(size_t)cc*9 + q] : 0.f;
  }
  if (tid < 32) bd[tid] = (cc0 + tid < 1551) ? dw1b[cc0 + tid] : 0.f;

  if (cc0 < 15){                                   // y1 channels [0,15) (chunk 0 only)
    int ny = 15;
    for (int i = tid; i < ny*196; i += 256){
      u32 c = (u32)i / 196u, p = (u32)i - c*196u;
      ms[c*202u + p] = y[((size_t)b*15 + c)*196 + p] * sse[b*15 + c];
    }
  }
  {                                                // z channels [15,527): pure gather
    int zs = cc0 > 15 ? cc0 : 15;
    int ze = cc0 + 32 < 527 ? cc0 + 32 : 527;
    if (zs < ze){
      int nz = ze - zs, lbase = zs - cc0, obase = zs - 15;
      const u16* zb = zT + (size_t)obase*26880 + (size_t)b*105;
      for (int i = tid; i < nz*196; i += 256){
        u32 oo = (u32)i / 196u, p = (u32)i - oo*196u;
        ms[(u32)(lbase + (int)oo)*202u + p] = bf2f(zb[(size_t)oo*26880 + ttab[p]]);
      }
    }
  }
  {                                                // x channels [527,1551): float4 loads
    int xs_ = cc0 > 527 ? cc0 : 527;
    int xe = cc0 + 32 < 1551 ? cc0 + 32 : 1551;
    if (xs_ < xe){
      int nx = xe - xs_, lbase = xs_ - cc0, cxs = xs_ - 527;
      const float4* xg = (const float4*)(x + ((size_t)b*1024 + cxs)*196);
      for (int i = tid; i < nx*49; i += 256){
        float4 v = xg[i];
        u32 c = (u32)i / 49u, p4 = (u32)i - c*49u;
        float* dst = &ms[(u32)(lbase + (int)c)*202u + p4*4u];
        float2 lo = {v.x, v.y}, hi = {v.z, v.w};
        *(float2*)dst = lo;
        *(float2*)(dst + 2) = hi;
      }
    }
  }
  {                                                // K pad [1551,1600) -> zeros
    int ps = cc0 > 1551 ? cc0 : 1551;
    int pe = cc0 + 32;
    if (ps < pe){
      int np = pe - ps, lbase = ps - cc0;
      for (int i = tid; i < np*196; i += 256){
        u32 c = (u32)i / 196u, p = (u32)i - c*196u;
        ms[(u32)(lbase + (int)c)*202u + p] = 0.f;
      }
    }
  }
  __syncthreads();

  for (int t = tid; t < 448; t += 256){            // conv: one thread = one (cc, out-row)
    int cc = t & 31, i = t >> 5;                   // lanes along cc -> coalesced stores
    float wr[9];
    #pragma unroll
    for (int qq = 0; qq < 9; ++qq) wr[qq] = wd[cc][qq];
    float topm = (i > 0) ? 1.f : 0.f, botm = (i < 13) ? 1.f : 0.f;
    wr[0] *= topm; wr[1] *= topm; wr[2] *= topm;
    wr[6] *= botm; wr[7] *= botm; wr[8] *= botm;
    float bb = bd[cc];
    float rr[3][16];
    #pragma unroll
    for (int d = 0; d < 3; ++d){
      rr[d][0] = 0.f; rr[d][15] = 0.f;
      int rowr = i + d - 1;
      rowr = rowr < 0 ? 0 : (rowr > 13 ? 13 : rowr);
      const float* src = &ms[cc*202 + rowr*14];
      #pragma unroll
      for (int j = 0; j < 7; ++j)
        *(float2*)&rr[d][1 + 2*j] = *(const float2*)&src[2*j];
    }
    size_t obase = ((size_t)b*196 + i*14) * 1600 + cc0 + cc;
    #pragma unroll
    for (int k = 0; k < 14; ++k){
      float a = bb;
      #pragma unroll
      for (int dy = 0; dy < 3; ++dy)
        #pragma unroll
        for (int dx = 0; dx < 3; ++dx)
          a += wr[dy*3+dx] * rr[dy][k + dx];
      Adw[obase + (size_t)k*1600] = f2bf(a);
    }
  }
}

// ---------------- NT GEMM v4 (r16): 128x128, BK=64, dbuf + counted vmcnt --------------
// MODE 0 (z): M'=26880 triangular; weighted BN stats; stores bf16 zT'[n][26880].
// MODE 1 (o): M=50176, f32 NCHW-transposed. XCD swizzle lin=(g&7)*per+(g>>3).
template<int MODE>
__global__ __launch_bounds__(256,2) void gemm_kernel(
    const u16* __restrict__ A, const u16* __restrict__ Bw,
    const float* __restrict__ bias, void* __restrict__ outp,
    float* __restrict__ stats, int K){
  __shared__ __align__(16) u16 lds[32768];         // 65,536 B: 2 x (A 16KB + B 16KB)

  int tid = threadIdx.x;
  int w = tid >> 6, l = tid & 63;
  int wm = w >> 1, wn = w & 1;
  int lr = l & 15, lq = l >> 4;
  u32 g = blockIdx.x;
  u32 per = gridDim.x >> 3;
  u32 lin = (g & 7u) * per + (g >> 3);
  int n0 = (int)(lin & 3u) * 128;
  int m0 = (int)(lin >> 2) * 128;

  f32x4 acc[4][4] = {};
  int kTiles = K >> 6;

  const u16* Abase = A  + (size_t)m0*K;
  const u16* Bbase = Bw + (size_t)n0*K;

  #pragma unroll
  for (int i = 0; i < 4; ++i){
    int s = tid + i*256;
    int row = s >> 3, c8 = s & 7, sc = c8 ^ (row & 7);
    GLDS16(Abase + (size_t)row*K + sc*8, lds + s*8);
    GLDS16(Bbase + (size_t)row*K + sc*8, lds + 8192 + s*8);
  }

  for (int kt = 0; kt < kTiles; ++kt){
    u32 bufo = (u32)(kt & 1) * 16384u;
    if (kt > 0) __builtin_amdgcn_s_barrier();
    if (kt + 1 < kTiles){
      u32 nbufo = bufo ^ 16384u;
      #pragma unroll
      for (int i = 0; i < 4; ++i){
        int s = tid + i*256;
        int row = s >> 3, c8 = s & 7, sc = c8 ^ (row & 7);
        GLDS16(Abase + (size_t)row*K + (kt+1)*64 + sc*8, lds + nbufo + s*8);
        GLDS16(Bbase + (size_t)row*K + (kt+1)*64 + sc*8, lds + nbufo + 8192 + s*8);
      }
      asm volatile("s_waitcnt vmcnt(8)" ::: "memory");
    } else {
      asm volatile("s_waitcnt vmcnt(0)" ::: "memory");
    }
    __builtin_amdgcn_s_barrier();
    asm volatile("" ::: "memory");
    const u16* Ac = lds + bufo;
    const u16* Bc = lds + bufo + 8192;
    #pragma unroll
    for (int ks = 0; ks < 2; ++ks){
      bf16x8 af[4], bfv[4];
      #pragma unroll
      for (int mi = 0; mi < 4; ++mi){
        int row = wm*64 + mi*16 + lr;
        int q = (ks*4 + lq) ^ (row & 7);
        af[mi] = *(const bf16x8*)(Ac + row*64 + q*8);
      }
      #pragma unroll
      for (int ni = 0; ni < 4; ++ni){
        int row = wn*64 + ni*16 + lr;
        int q = (ks*4 + lq) ^ (row & 7);
        bfv[ni] = *(const bf16x8*)(Bc + row*64 + q*8);
      }
      #pragma unroll
      for (int mi = 0; mi < 4; ++mi)
        #pragma unroll
        for (int ni = 0; ni < 4; ++ni)
          acc[mi][ni] = __builtin_amdgcn_mfma_f32_16x16x32_bf16(af[mi], bfv[ni], acc[mi][ni], 0, 0, 0);
    }
  }
  __syncthreads();

  // row weights for triangular mode (1 diag, 2 off-diag)
  float wgt16[4][4];
  if (MODE == 0){
    float* wrow = (float*)lds + 8320;              // beyond 2x[64][65] transpose region
    for (int rb = tid; rb < 128; rb += 256){
      u32 t = (u32)(m0 + rb) % 105u;
      float wgt = 2.f;
      #pragma unroll
      for (int ii = 0; ii < 14; ++ii){
        int td = 14*ii - (ii*(ii-1))/2;
        if ((int)t == td) wgt = 1.f;
      }
      wrow[rb] = wgt;
    }
    __syncthreads();
    #pragma unroll
    for (int mi = 0; mi < 4; ++mi)
      #pragma unroll
      for (int r = 0; r < 4; ++r)
        wgt16[mi][r] = wrow[wm*64 + mi*16 + lq*4 + r];
  }

  // bias + per-column BN stats (sum, sumsq)
  #pragma unroll
  for (int ni = 0; ni < 4; ++ni){
    int col = n0 + wn*64 + ni*16 + lr;
    float bb = bias[col];
    float s1 = 0.f, s2 = 0.f;
    #pragma unroll
    for (int mi = 0; mi < 4; ++mi)
      #pragma unroll
      for (int r = 0; r < 4; ++r){
        float v = acc[mi][ni][r] + bb;
        acc[mi][ni][r] = v;
        float wv = (MODE == 0) ? wgt16[mi][r] : 1.f;
        s1 += wv*v; s2 += wv*v*v;
      }
    s1 += __shfl_xor(s1, 16); s1 += __shfl_xor(s1, 32);
    s2 += __shfl_xor(s2, 16); s2 += __shfl_xor(s2, 32);
    if (lq == 0){
      atomicAdd(&stats[col], s1);
      atomicAdd(&stats[512 + col], s2);
    }
  }

  float* eb = (float*)lds;
  #pragma unroll
  for (int rnd = 0; rnd < 2; ++rnd){
    if (wm == rnd){
      float* e = eb + wn * (64*65);
      #pragma unroll
      for (int mi = 0; mi < 4; ++mi)
        #pragma unroll
        for (int ni = 0; ni < 4; ++ni)
          #pragma unroll
          for (int r = 0; r < 4; ++r)
            e[(mi*16 + lq*4 + r)*65 + ni*16 + lr] = acc[mi][ni][r];
      int m = m0 + wm*64 + l;
      if (MODE == 0){
        u16* ob = (u16*)outp + (size_t)(n0 + wn*64)*26880 + m;
        #pragma unroll 8
        for (int no = 0; no < 64; ++no)
          ob[(size_t)no*26880] = f2bf(e[l*65 + no]);
      } else {
        u32 bq = (u32)m / 196u;
        u32 ij = (u32)m - bq*196u;
        float* ob = (float*)outp + ((size_t)bq*512 + n0 + wn*64)*196 + ij;
        #pragma unroll 8
        for (int no = 0; no < 64; ++no)
          ob[(size_t)no*196] = e[l*65 + no];
      }
    }
    __syncthreads();
  }
}

// ---------------- BN prep: stats -> scale/shift ----------------
__global__ void bnprep_kernel(const float* __restrict__ stats, const float* __restrict__ gamma,
    const float* __restrict__ beta, float* __restrict__ sc, float* __restrict__ sh){
  int o = threadIdx.x;
  float m = stats[o] * (1.f/50176.f);
  float v = stats[512+o] * (1.f/50176.f) - m*m;
  float inv = rsqrtf(v + EPSBN);
  float g = gamma[o] * inv;
  sc[o] = g;
  sh[o] = beta[o] - m*g;
}

// ---------------- final: relu(bn(o)) in place on d_out (NCHW) ----------------
__global__ void final_kernel(float4* __restrict__ o4, const float* __restrict__ sc,
                             const float* __restrict__ sh){
  u32 stride = gridDim.x * blockDim.x;
  for (u32 i = blockIdx.x*blockDim.x + threadIdx.x; i < 6422528u; i += stride){
    u32 oc = (i / 49u) & 511u;
    float s = sc[oc], t = sh[oc];
    float4 v = o4[i];
    v.x = fmaxf(fmaf(v.x, s, t), 0.f);
    v.y = fmaxf(fmaf(v.y, s, t), 0.f);
    v.z = fmaxf(fmaf(v.z, s, t), 0.f);
    v.w = fmaxf(fmaf(v.w, s, t), 0.f);
    o4[i] = v;
  }
}

extern "C" void kernel_launch(void* const* d_in, const int* in_sizes, int n_in,
                              void* d_out, int out_size, void* d_ws, size_t ws_size,
                              hipStream_t stream){
  (void)in_sizes; (void)n_in; (void)out_size; (void)ws_size;
  const float* y      = (const float*)d_in[0];
  const float* x      = (const float*)d_in[1];
  const float* fc1    = (const float*)d_in[2];
  const float* fc2    = (const float*)d_in[3];
  const float* convw  = (const float*)d_in[4];
  const float* convb  = (const float*)d_in[5];
  const float* dconvw = (const float*)d_in[6];
  const float* dconvb = (const float*)d_in[7];
  const float* dw1w   = (const float*)d_in[8];
  const float* dw1b   = (const float*)d_in[9];
  const float* pw1w   = (const float*)d_in[10];
  const float* pw1b   = (const float*)d_in[11];
  const float* gamma  = (const float*)d_in[12];
  const float* beta   = (const float*)d_in[13];

  char* ws = (char*)d_ws;
  u16* covT   = (u16*)(ws + OFF_COVT);
  u16* Adw    = (u16*)(ws + OFF_ADW);
  float* sse  = (float*)(ws + OFF_S);
  u16* wbz    = (u16*)(ws + OFF_WBZ);
  u16* wbp    = (u16*)(ws + OFF_WBP);
  float* statsZ = (float*)(ws + OFF_STATSZ);
  float* statsO = (float*)(ws + OFF_STATSO);
  float* scz  = (float*)(ws + OFF_SCZ);
  float* shz  = (float*)(ws + OFF_SHZ);
  float* sco  = (float*)(ws + OFF_SCO);
  float* sho  = (float*)(ws + OFF_SHO);
  u16* zT     = (u16*)d_out;      // triangular z [512][26880] bf16 in d_out, dead before o written
  float* outf = (float*)d_out;

  hipMemsetAsync(statsZ, 0, 8192, stream);
  se_kernel<<<256, 64, 0, stream>>>(y, fc1, fc2, sse);
  wconv_kernel<<<2048, 256, 0, stream>>>(convw, pw1w, wbz, wbp);
  cov_kernel<<<dim3(16, 256), 256, 0, stream>>>(x, dconvw, dconvb, covT);
  gemm_kernel<0><<<840, 256, 0, stream>>>(covT, wbz, convb, (void*)zT, statsZ, 1024);
  bnprep_kernel<<<1, 512, 0, stream>>>(statsZ, gamma, beta, scz, shz);
  zsig_kernel<<<2048, 256, 0, stream>>>((u32*)zT, scz, shz);
  adw_kernel<<<dim3(50, 256), 256, 0, stream>>>(y, sse, zT, x, dw1w, dw1b, Adw);
  gemm_kernel<1><<<1568, 256, 0, stream>>>(Adw, wbp, pw1b, (void*)outf, statsO, 1600);
  bnprep_kernel<<<1, 512, 0, stream>>>(statsO, gamma, beta, sco, sho);
  final_kernel<<<8192, 256, 0, stream>>>((float4*)outf, sco, sho);
}